// Round 16
// baseline (118.854 us; speedup 1.0000x reference)
//
#include <hip/hip_runtime.h>

#define SEQ 2048
#define NTOK 4096
#define DIM 1024
#define FQKV 3072
#define SC_Q (0.08838834764831843f * 1.4426950408889634f)  // 128^-.5 * log2e
#define SC_NORM 32.0f                  // sqrt(1024)

typedef short short8 __attribute__((ext_vector_type(8)));
typedef float f32x4 __attribute__((ext_vector_type(4)));
typedef unsigned short u16x4 __attribute__((ext_vector_type(4)));

__device__ __forceinline__ unsigned short f2bf(float f) {
    unsigned int u = __float_as_uint(f);
    u += 0x7fffu + ((u >> 16) & 1u);   // RNE
    return (unsigned short)(u >> 16);
}
__device__ __forceinline__ float bf2f(unsigned short b) {
    return __uint_as_float(((unsigned int)b) << 16);
}
__device__ __forceinline__ void gl_lds16(const void* g, void* l) {
    __builtin_amdgcn_global_load_lds((const __attribute__((address_space(1))) void*)g,
                                     (__attribute__((address_space(3))) void*)l, 16, 0, 0);
}

// ---------------------------------------------------------------------------
// prep: blocks [0,4096) = L2-norm per token; blocks [4096,8192) = weight conv
// ---------------------------------------------------------------------------
__global__ __launch_bounds__(256) void prep(const float* __restrict__ x,
                                            const float* __restrict__ gamma,
                                            unsigned short* __restrict__ xn,
                                            const float* __restrict__ wq,
                                            unsigned short* __restrict__ wqb,
                                            const float* __restrict__ wo,
                                            unsigned short* __restrict__ wob) {
    if (blockIdx.x < 4096) {
        int token = blockIdx.x;
        float4 v = ((const float4*)(x + (size_t)token * DIM))[threadIdx.x];
        float ss = v.x * v.x + v.y * v.y + v.z * v.z + v.w * v.w;
#pragma unroll
        for (int off = 32; off > 0; off >>= 1) ss += __shfl_down(ss, off);
        __shared__ float wsum[4];
        if ((threadIdx.x & 63) == 0) wsum[threadIdx.x >> 6] = ss;
        __syncthreads();
        float tot = wsum[0] + wsum[1] + wsum[2] + wsum[3];
        float sc = SC_NORM / fmaxf(sqrtf(tot), 1e-12f);
        float4 g = ((const float4*)gamma)[threadIdx.x];
        u16x4 o;
        o.x = f2bf(v.x * sc * g.x);
        o.y = f2bf(v.y * sc * g.y);
        o.z = f2bf(v.z * sc * g.z);
        o.w = f2bf(v.w * sc * g.w);
        ((u16x4*)(xn + (size_t)token * DIM))[threadIdx.x] = o;
    } else {
        int i = (blockIdx.x - 4096) * 256 + threadIdx.x;   // f4 index, 1048576 total
        const float* w; unsigned short* o; int idx;
        if (i < 786432) { w = wq; o = wqb; idx = i; }
        else            { w = wo; o = wob; idx = i - 786432; }
        float4 v = ((const float4*)w)[idx];
        u16x4 r;
        r.x = f2bf(v.x); r.y = f2bf(v.y); r.z = f2bf(v.z); r.w = f2bf(v.w);
        ((u16x4*)o)[idx] = r;
    }
}

// ---------------------------------------------------------------------------
// bf16 GEMM NT (R8 inner loop): TM x 128 tile, BK=64, single-buffer split-
// phase raw barriers, 2D XCD chunking.
// ---------------------------------------------------------------------------
template<int C_MODE, int TM, int XC>
__global__ __launch_bounds__(256) void gemm_bf16(const unsigned short* __restrict__ A,
                                                 const unsigned short* __restrict__ B,
                                                 void* __restrict__ Cv,
                                                 int M, int N, int K) {
    constexpr int MF = TM / 32;
    __shared__ unsigned short As[TM * 64];
    __shared__ unsigned short Bs[128 * 64];

    // 2D-chunked XCD swizzle (bijective; assumes block n -> XCD n%8)
    int lin = blockIdx.y * gridDim.x + blockIdx.x;
    int xcd = lin & 7, i = lin >> 3;
    int CW = gridDim.x / XC;               // chunk width (tiles)
    int CH = gridDim.y / (8 / XC);         // chunk height (tiles)
    int bx = (xcd % XC) * CW + (i % CW);
    int by = (xcd / XC) * CH + (i / CW);

    const int bn = bx * 128, bm = by * TM;
    const int tid = threadIdx.x, lane = tid & 63, wv = tid >> 6;
    const int wr = wv >> 1, wc = wv & 1;
    const int l15 = lane & 15, g = lane >> 4;

    f32x4 acc[MF][4] = {};

    auto stage = [&](int k0) {
#pragma unroll
        for (int ia = 0; ia < TM / 32; ++ia) {
            int ci = ia * 256 + wv * 64 + lane;
            int row = ci >> 3, cc = ci & 7;
            int co = (cc ^ (row & 7)) << 3;
            gl_lds16(A + (size_t)(bm + row) * K + k0 + co, &As[(ia * 256 + wv * 64) * 8]);
        }
#pragma unroll
        for (int ib = 0; ib < 4; ++ib) {
            int ci = ib * 256 + wv * 64 + lane;
            int row = ci >> 3, cc = ci & 7;
            int co = (cc ^ (row & 7)) << 3;
            gl_lds16(B + (size_t)(bn + row) * K + k0 + co, &Bs[(ib * 256 + wv * 64) * 8]);
        }
    };

    stage(0);
    asm volatile("s_waitcnt vmcnt(0)\ns_barrier" ::: "memory");

    for (int k0 = 0; k0 < K; k0 += 64) {
        short8 af[2][MF], bf[2][4];
#pragma unroll
        for (int ks = 0; ks < 2; ++ks) {
#pragma unroll
            for (int f = 0; f < MF; ++f) {
                int ra = wr * (TM / 2) + f * 16 + l15;
                af[ks][f] = *(const short8*)&As[ra * 64 + (((ks * 4 + g) ^ (ra & 7)) << 3)];
            }
#pragma unroll
            for (int f = 0; f < 4; ++f) {
                int rb = wc * 64 + f * 16 + l15;
                bf[ks][f] = *(const short8*)&Bs[rb * 64 + (((ks * 4 + g) ^ (rb & 7)) << 3)];
            }
        }
        asm volatile("s_waitcnt lgkmcnt(0)\ns_barrier" ::: "memory");
        if (k0 + 64 < K) stage(k0 + 64);
#pragma unroll
        for (int ks = 0; ks < 2; ++ks)
#pragma unroll
            for (int i2 = 0; i2 < MF; ++i2)
#pragma unroll
                for (int j = 0; j < 4; ++j)
                    acc[i2][j] = __builtin_amdgcn_mfma_f32_16x16x32_bf16(af[ks][i2], bf[ks][j], acc[i2][j], 0, 0, 0);
        asm volatile("s_waitcnt vmcnt(0)\ns_barrier" ::: "memory");
    }

    if (C_MODE == 0) {
        float* C = (float*)Cv;
#pragma unroll
        for (int i2 = 0; i2 < MF; ++i2)
#pragma unroll
            for (int j = 0; j < 4; ++j)
#pragma unroll
                for (int v = 0; v < 4; ++v) {
                    int row = bm + wr * (TM / 2) + i2 * 16 + g * 4 + v;
                    int col = bn + wc * 64 + j * 16 + l15;
                    C[(size_t)row * N + col] = acc[i2][j][v];
                }
    } else {
        unsigned short* C = (unsigned short*)Cv;
        float s = (bn < 1024) ? SC_Q : 1.0f;
#pragma unroll
        for (int i2 = 0; i2 < MF; ++i2)
#pragma unroll
            for (int j = 0; j < 4; ++j)
#pragma unroll
                for (int v = 0; v < 4; ++v) {
                    int row = bm + wr * (TM / 2) + i2 * 16 + g * 4 + v;
                    int col = bn + wc * 64 + j * 16 + l15;
                    C[(size_t)row * N + col] = f2bf(acc[i2][j][v] * s);
                }
    }
}

// ---------------------------------------------------------------------------
// V transpose: qkv V-part [token][d] -> vt[(b*8+h)*128 + d][token]
// ---------------------------------------------------------------------------
__global__ __launch_bounds__(256) void transpose_v(const unsigned short* __restrict__ qkv,
                                                   unsigned short* __restrict__ vt) {
    __shared__ unsigned short T[64][72];
    const int t0 = blockIdx.x * 64, d0 = blockIdx.y * 64, bh = blockIdx.z;
    const int b = bh >> 3, h = bh & 7;
    const int tid = threadIdx.x;
#pragma unroll
    for (int p = 0; p < 2; ++p) {
        int r = p * 32 + (tid >> 3), c = tid & 7;
        *(short8*)&T[r][c * 8] =
            *(const short8*)(qkv + (size_t)(b * SEQ + t0 + r) * FQKV + 2048 + h * 128 + d0 + c * 8);
    }
    __syncthreads();
#pragma unroll
    for (int p = 0; p < 2; ++p) {
        int d = p * 32 + (tid >> 3), c = tid & 7;
        short8 v;
#pragma unroll
        for (int j = 0; j < 8; ++j) v[j] = (short)T[c * 8 + j][d];
        *(short8*)(vt + (size_t)(bh * 128 + d0 + d) * SEQ + t0 + c * 8) = v;
    }
}

// ---------------------------------------------------------------------------
// Flash attention (R15 structure) with loop-invariant address hoisting:
// (1) LDS read addresses (kaddr[4][4], vaddr[2][8]) precomputed before the
//     jb-loop into registers (VGPR 80 showed the compiler rematerialized
//     ~170 addr ops/tile instead of hoisting);
// (2) staging uses running pointers kp[4]/vp[4] advanced by tile stride
//     (8 adds/tile replace ~48 mul-chain ops).
// ---------------------------------------------------------------------------
__global__ __launch_bounds__(256) void attn_mfma(const unsigned short* __restrict__ qkv,
                                                 const unsigned short* __restrict__ vt,
                                                 unsigned short* __restrict__ ao,
                                                 unsigned short* __restrict__ po,
                                                 float* __restrict__ pml) {
    __shared__ unsigned short Ks[64 * 128];
    __shared__ unsigned short Vs[128 * 64];
    __shared__ unsigned short Ps[4][16 * 64];
    const int h = blockIdx.y, b = blockIdx.z;
    const int x = blockIdx.x;
    int qblk, s, nsp;
    if (x < 30)      { qblk = 27 - x / 3;               s = x % 3;  nsp = 3; }
    else if (x < 46) { int i = x - 30; qblk = 31 - (i >> 2); s = i & 3; nsp = 4; }
    else if (x < 64) { int i = x - 46; qblk = 17 - (i >> 1); s = i & 1; nsp = 2; }
    else             { qblk = 72 - x;                   s = 0;      nsp = 1; }
    const int T = qblk + 1;
    const int jb0 = (s * T) / nsp, jb1 = ((s + 1) * T) / nsp;
    const int split = (nsp > 1);
    const int slot = ((b * 8 + h) << 6) + x;          // valid when split (x<64)

    const int tid = threadIdx.x, lane = tid & 63, wv = tid >> 6;
    const int l15 = lane & 15, g = lane >> 4;
    const int q0 = qblk * 64;
    const int qrow = q0 + wv * 16 + l15;

    // ---- hoisted LDS read addresses (element offsets), static-indexed ----
    int kaddr[4][4], vaddr[2][8], praddr[2];
#pragma unroll
    for (int ks = 0; ks < 4; ++ks)
#pragma unroll
        for (int fi = 0; fi < 4; ++fi) {
            int rk = fi * 16 + l15;
            kaddr[ks][fi] = rk * 128 + (((ks * 4 + g) ^ (rk & 7)) << 3);
        }
#pragma unroll
    for (int ks = 0; ks < 2; ++ks) {
#pragma unroll
        for (int fn = 0; fn < 8; ++fn) {
            int rv = fn * 16 + l15;
            vaddr[ks][fn] = rv * 64 + (((ks * 4 + g) ^ (rv & 7)) << 3);
        }
        praddr[ks] = l15 * 64 + (((ks * 4 + g) ^ (l15 & 7)) << 3);
    }

    // ---- running staging pointers (pre-swizzled source), advanced per tile --
    const unsigned short* kp[4];
    const unsigned short* vp[4];
#pragma unroll
    for (int inst = 0; inst < 4; ++inst) {
        int ci = inst * 256 + wv * 64 + lane;
        int rowk = ci >> 4, ck = ci & 15;
        kp[inst] = qkv + (size_t)(b * SEQ + jb0 * 64 + rowk) * FQKV + 1024 + h * 128
                       + ((ck ^ (rowk & 7)) << 3);
        int rowv = ci >> 3, cv = ci & 7;
        vp[inst] = vt + (size_t)((b * 8 + h) * 128 + rowv) * SEQ + jb0 * 64
                      + ((cv ^ (rowv & 7)) << 3);
    }
    const int ldsK = (wv * 64 + lane) * 8;   // per-inst LDS dest stride 256*8

    auto stageK = [&]() {                    // issues at current kp, then advances
#pragma unroll
        for (int inst = 0; inst < 4; ++inst) {
            gl_lds16(kp[inst], &Ks[inst * 2048 + ldsK]);
            kp[inst] += 64 * FQKV;
        }
    };
    auto stageV = [&]() {
#pragma unroll
        for (int inst = 0; inst < 4; ++inst) {
            gl_lds16(vp[inst], &Vs[inst * 2048 + ldsK]);
            vp[inst] += 64;
        }
    };

    short8 qf[4];
    {
        const unsigned short* qb = qkv + (size_t)(b * SEQ + qrow) * FQKV + h * 128;
#pragma unroll
        for (int ks = 0; ks < 4; ++ks) qf[ks] = *(const short8*)(qb + ks * 32 + g * 8);
    }

    float m_r = -1e30f, l_r = 0.f;
    f32x4 o[8] = {};

    stageK();
    __syncthreads();

    for (int jb = jb0; jb < jb1; ++jb) {
        stageV();

        f32x4 sv[4] = {};
        __builtin_amdgcn_s_setprio(1);
#pragma unroll
        for (int ks = 0; ks < 4; ++ks) {
#pragma unroll
            for (int fi = 0; fi < 4; ++fi) {
                short8 kf = *(const short8*)&Ks[kaddr[ks][fi]];
                sv[fi] = __builtin_amdgcn_mfma_f32_16x16x32_bf16(kf, qf[ks], sv[fi], 0, 0, 0);
            }
        }
        __builtin_amdgcn_s_setprio(0);

        if (jb == qblk) {
#pragma unroll
            for (int fi = 0; fi < 4; ++fi)
#pragma unroll
                for (int v = 0; v < 4; ++v) {
                    int kv = q0 + fi * 16 + g * 4 + v;
                    if (kv > qrow) sv[fi][v] = -1e30f;
                }
        }

        float mx = -1e30f;
#pragma unroll
        for (int fi = 0; fi < 4; ++fi)
            mx = fmaxf(mx, fmaxf(fmaxf(sv[fi][0], sv[fi][1]), fmaxf(sv[fi][2], sv[fi][3])));
        mx = fmaxf(mx, __shfl_xor(mx, 16));
        mx = fmaxf(mx, __shfl_xor(mx, 32));
        if (__any(mx - m_r > 16.0f)) {
            float Mn = fmaxf(m_r, mx);
            float alpha = exp2f(m_r - Mn);
            l_r *= alpha;
            float av[4];
#pragma unroll
            for (int v = 0; v < 4; ++v) av[v] = __shfl(alpha, g * 4 + v);
#pragma unroll
            for (int fn = 0; fn < 8; ++fn) {
                o[fn][0] *= av[0]; o[fn][1] *= av[1]; o[fn][2] *= av[2]; o[fn][3] *= av[3];
            }
            m_r = Mn;
        }

        float ps = 0.f;
#pragma unroll
        for (int fi = 0; fi < 4; ++fi) {
#pragma unroll
            for (int p2 = 0; p2 < 2; ++p2) {
                float e0 = exp2f(sv[fi][2 * p2] - m_r);
                float e1 = exp2f(sv[fi][2 * p2 + 1] - m_r);
                ps += e0 + e1;
                unsigned int pk;
                asm("v_cvt_pk_bf16_f32 %0, %1, %2" : "=v"(pk) : "v"(e0), "v"(e1));
                int kv = fi * 16 + g * 4 + 2 * p2;
                int addr = l15 * 64 + (((kv >> 3) ^ (l15 & 7)) << 3) + (kv & 7);
                *(unsigned int*)&Ps[wv][addr] = pk;
            }
        }
        ps += __shfl_xor(ps, 16);
        ps += __shfl_xor(ps, 32);
        l_r += ps;

        __syncthreads();
        if (jb + 1 < jb1) stageK();

        __builtin_amdgcn_s_setprio(1);
#pragma unroll
        for (int ks = 0; ks < 2; ++ks) {
            short8 pa = *(const short8*)&Ps[wv][praddr[ks]];
#pragma unroll
            for (int fn = 0; fn < 8; ++fn) {
                short8 vf = *(const short8*)&Vs[vaddr[ks][fn]];
                o[fn] = __builtin_amdgcn_mfma_f32_16x16x32_bf16(pa, vf, o[fn], 0, 0, 0);
            }
        }
        __builtin_amdgcn_s_setprio(0);

        __syncthreads();
    }

    if (split) {
        unsigned short* od = po + (size_t)slot * 8192;   // bf16 partial O
#pragma unroll
        for (int fn = 0; fn < 8; ++fn)
#pragma unroll
            for (int v = 0; v < 4; ++v)
                od[(wv * 16 + g * 4 + v) * 128 + fn * 16 + l15] = f2bf(o[fn][v]);
        if (g == 0) {
            pml[(size_t)slot * 128 + wv * 16 + l15] = m_r;
            pml[(size_t)slot * 128 + 64 + wv * 16 + l15] = l_r;
        }
    } else {
        float lv[4];
#pragma unroll
        for (int v = 0; v < 4; ++v) lv[v] = 1.0f / __shfl(l_r, g * 4 + v);
#pragma unroll
        for (int fn = 0; fn < 8; ++fn)
#pragma unroll
            for (int v = 0; v < 4; ++v) {
                int row = b * SEQ + q0 + wv * 16 + g * 4 + v;
                ao[(size_t)row * DIM + h * 128 + fn * 16 + l15] = f2bf(o[fn][v] * lv[v]);
            }
    }
}

// ---------------------------------------------------------------------------
// Combine n in {2,3,4} KV-split partials -> normalized bf16 output (R9).
// ---------------------------------------------------------------------------
__global__ __launch_bounds__(256) void attn_combine(const unsigned short* __restrict__ po,
                                                    const float* __restrict__ pml,
                                                    unsigned short* __restrict__ ao) {
    const int qblk = 9 + blockIdx.x, h = blockIdx.y, b = blockIdx.z;
    int base, n;
    if (qblk >= 28)      { base = 30 + (31 - qblk) * 4; n = 4; }
    else if (qblk >= 18) { base = (27 - qblk) * 3;      n = 3; }
    else                 { base = 46 + (17 - qblk) * 2; n = 2; }
    const int slot0 = ((b * 8 + h) << 6) + base;
    const int row = threadIdx.x >> 2, dp = threadIdx.x & 3;

    float M = -1e30f;
#pragma unroll
    for (int s2 = 0; s2 < 4; ++s2)
        if (s2 < n) M = fmaxf(M, pml[(size_t)(slot0 + s2) * 128 + row]);
    float denom = 0.f;
#pragma unroll
    for (int s2 = 0; s2 < 4; ++s2)
        if (s2 < n) denom += exp2f(pml[(size_t)(slot0 + s2) * 128 + row] - M)
                             * pml[(size_t)(slot0 + s2) * 128 + 64 + row];
    float inv = 1.0f / denom;

    float acc[32] = {};
#pragma unroll
    for (int s2 = 0; s2 < 4; ++s2)
        if (s2 < n) {
            float wgt = exp2f(pml[(size_t)(slot0 + s2) * 128 + row] - M) * inv;
            const unsigned short* ob = po + (size_t)(slot0 + s2) * 8192 + row * 128 + dp * 32;
#pragma unroll
            for (int j = 0; j < 4; ++j) {
                short8 pv = *(const short8*)(ob + j * 8);
#pragma unroll
                for (int e = 0; e < 8; ++e)
                    acc[j * 8 + e] += wgt * bf2f((unsigned short)pv[e]);
            }
        }

    unsigned short* dst = ao + ((size_t)(b * SEQ + qblk * 64 + row)) * DIM + h * 128 + dp * 32;
#pragma unroll
    for (int j = 0; j < 4; ++j) {
        short8 r;
#pragma unroll
        for (int e = 0; e < 8; ++e) r[e] = (short)f2bf(acc[j * 8 + e]);
        *(short8*)(dst + j * 8) = r;
    }
}

// ---------------------------------------------------------------------------
extern "C" void kernel_launch(void* const* d_in, const int* in_sizes, int n_in,
                              void* d_out, int out_size, void* d_ws, size_t ws_size,
                              hipStream_t stream) {
    const float* x     = (const float*)d_in[0];
    const float* gamma = (const float*)d_in[1];
    const float* w_qkv = (const float*)d_in[2];
    const float* w_out = (const float*)d_in[3];

    char* ws = (char*)d_ws;
    unsigned short* qkvb = (unsigned short*)ws;                   // 25165824 B  [4096][3072]
    unsigned short* vtb  = (unsigned short*)(ws + 25165824);      //  8388608 B  [16][128][2048]
    unsigned short* xnb  = (unsigned short*)(ws + 33554432);      //  8388608 B  [4096][1024]
    unsigned short* wqb  = (unsigned short*)(ws + 41943040);      //  6291456 B  [3072][1024]
    unsigned short* wob  = (unsigned short*)(ws + 48234496);      //  2097152 B  [1024][1024]
    unsigned short* aob  = (unsigned short*)(ws + 50331648);      //  8388608 B  [4096][1024]
    // pml overlaps wqb (dead after gemm1): 1024 slots x 128 f32 = 512 KB
    float*          pml  = (float*)(ws + 41943040);
    unsigned short* po   = (unsigned short*)d_out;  // 1024 slots x 64x128 bf16 = 16.78 MB

    prep<<<8192, 256, 0, stream>>>(x, gamma, xnb, w_qkv, wqb, w_out, wob);
    gemm_bf16<1, 128, 2><<<dim3(24, 32), 256, 0, stream>>>(xnb, wqb, qkvb, NTOK, FQKV, DIM);
    transpose_v<<<dim3(32, 2, 16), 256, 0, stream>>>(qkvb, vtb);
    attn_mfma<<<dim3(73, 8, 2), 256, 0, stream>>>(qkvb, vtb, aob, po, pml);
    attn_combine<<<dim3(23, 8, 2), 256, 0, stream>>>(po, pml, aob);
    gemm_bf16<0, 64, 1><<<dim3(8, 64), 256, 0, stream>>>(aob, wob, (float*)d_out, NTOK, DIM, DIM);
}

// Round 17
// 115.887 us; speedup vs baseline: 1.0256x; 1.0256x over previous
//
#include <hip/hip_runtime.h>

#define SEQ 2048
#define NTOK 4096
#define DIM 1024
#define FQKV 3072
#define SC_Q (0.08838834764831843f * 1.4426950408889634f)  // 128^-.5 * log2e
#define SC_NORM 32.0f                  // sqrt(1024)

typedef short short8 __attribute__((ext_vector_type(8)));
typedef float f32x4 __attribute__((ext_vector_type(4)));
typedef unsigned short u16x4 __attribute__((ext_vector_type(4)));

__device__ __forceinline__ unsigned short f2bf(float f) {
    unsigned int u = __float_as_uint(f);
    u += 0x7fffu + ((u >> 16) & 1u);   // RNE
    return (unsigned short)(u >> 16);
}
__device__ __forceinline__ float bf2f(unsigned short b) {
    return __uint_as_float(((unsigned int)b) << 16);
}
__device__ __forceinline__ void gl_lds16(const void* g, void* l) {
    __builtin_amdgcn_global_load_lds((const __attribute__((address_space(1))) void*)g,
                                     (__attribute__((address_space(3))) void*)l, 16, 0, 0);
}

// ---------------------------------------------------------------------------
// prep: blocks [0,4096) = L2-norm per token; blocks [4096,8192) = weight conv
// ---------------------------------------------------------------------------
__global__ __launch_bounds__(256) void prep(const float* __restrict__ x,
                                            const float* __restrict__ gamma,
                                            unsigned short* __restrict__ xn,
                                            const float* __restrict__ wq,
                                            unsigned short* __restrict__ wqb,
                                            const float* __restrict__ wo,
                                            unsigned short* __restrict__ wob) {
    if (blockIdx.x < 4096) {
        int token = blockIdx.x;
        float4 v = ((const float4*)(x + (size_t)token * DIM))[threadIdx.x];
        float ss = v.x * v.x + v.y * v.y + v.z * v.z + v.w * v.w;
#pragma unroll
        for (int off = 32; off > 0; off >>= 1) ss += __shfl_down(ss, off);
        __shared__ float wsum[4];
        if ((threadIdx.x & 63) == 0) wsum[threadIdx.x >> 6] = ss;
        __syncthreads();
        float tot = wsum[0] + wsum[1] + wsum[2] + wsum[3];
        float sc = SC_NORM / fmaxf(sqrtf(tot), 1e-12f);
        float4 g = ((const float4*)gamma)[threadIdx.x];
        u16x4 o;
        o.x = f2bf(v.x * sc * g.x);
        o.y = f2bf(v.y * sc * g.y);
        o.z = f2bf(v.z * sc * g.z);
        o.w = f2bf(v.w * sc * g.w);
        ((u16x4*)(xn + (size_t)token * DIM))[threadIdx.x] = o;
    } else {
        int i = (blockIdx.x - 4096) * 256 + threadIdx.x;   // f4 index, 1048576 total
        const float* w; unsigned short* o; int idx;
        if (i < 786432) { w = wq; o = wqb; idx = i; }
        else            { w = wo; o = wob; idx = i - 786432; }
        float4 v = ((const float4*)w)[idx];
        u16x4 r;
        r.x = f2bf(v.x); r.y = f2bf(v.y); r.z = f2bf(v.z); r.w = f2bf(v.w);
        ((u16x4*)o)[idx] = r;
    }
}

// ---------------------------------------------------------------------------
// bf16 GEMM NT (R8 inner loop): TM x 128 tile, BK=64, single-buffer split-
// phase raw barriers, 2D XCD chunking. At the validated 2-phase plateau
// (~740 TF ~= catalog m230-V0/m248); next lever is the 8-phase 256² port.
// ---------------------------------------------------------------------------
template<int C_MODE, int TM, int XC>
__global__ __launch_bounds__(256) void gemm_bf16(const unsigned short* __restrict__ A,
                                                 const unsigned short* __restrict__ B,
                                                 void* __restrict__ Cv,
                                                 int M, int N, int K) {
    constexpr int MF = TM / 32;
    __shared__ unsigned short As[TM * 64];
    __shared__ unsigned short Bs[128 * 64];

    // 2D-chunked XCD swizzle (bijective; assumes block n -> XCD n%8)
    int lin = blockIdx.y * gridDim.x + blockIdx.x;
    int xcd = lin & 7, i = lin >> 3;
    int CW = gridDim.x / XC;               // chunk width (tiles)
    int CH = gridDim.y / (8 / XC);         // chunk height (tiles)
    int bx = (xcd % XC) * CW + (i % CW);
    int by = (xcd / XC) * CH + (i / CW);

    const int bn = bx * 128, bm = by * TM;
    const int tid = threadIdx.x, lane = tid & 63, wv = tid >> 6;
    const int wr = wv >> 1, wc = wv & 1;
    const int l15 = lane & 15, g = lane >> 4;

    f32x4 acc[MF][4] = {};

    auto stage = [&](int k0) {
#pragma unroll
        for (int ia = 0; ia < TM / 32; ++ia) {
            int ci = ia * 256 + wv * 64 + lane;
            int row = ci >> 3, cc = ci & 7;
            int co = (cc ^ (row & 7)) << 3;
            gl_lds16(A + (size_t)(bm + row) * K + k0 + co, &As[(ia * 256 + wv * 64) * 8]);
        }
#pragma unroll
        for (int ib = 0; ib < 4; ++ib) {
            int ci = ib * 256 + wv * 64 + lane;
            int row = ci >> 3, cc = ci & 7;
            int co = (cc ^ (row & 7)) << 3;
            gl_lds16(B + (size_t)(bn + row) * K + k0 + co, &Bs[(ib * 256 + wv * 64) * 8]);
        }
    };

    stage(0);
    asm volatile("s_waitcnt vmcnt(0)\ns_barrier" ::: "memory");

    for (int k0 = 0; k0 < K; k0 += 64) {
        short8 af[2][MF], bf[2][4];
#pragma unroll
        for (int ks = 0; ks < 2; ++ks) {
#pragma unroll
            for (int f = 0; f < MF; ++f) {
                int ra = wr * (TM / 2) + f * 16 + l15;
                af[ks][f] = *(const short8*)&As[ra * 64 + (((ks * 4 + g) ^ (ra & 7)) << 3)];
            }
#pragma unroll
            for (int f = 0; f < 4; ++f) {
                int rb = wc * 64 + f * 16 + l15;
                bf[ks][f] = *(const short8*)&Bs[rb * 64 + (((ks * 4 + g) ^ (rb & 7)) << 3)];
            }
        }
        asm volatile("s_waitcnt lgkmcnt(0)\ns_barrier" ::: "memory");
        if (k0 + 64 < K) stage(k0 + 64);
#pragma unroll
        for (int ks = 0; ks < 2; ++ks)
#pragma unroll
            for (int i2 = 0; i2 < MF; ++i2)
#pragma unroll
                for (int j = 0; j < 4; ++j)
                    acc[i2][j] = __builtin_amdgcn_mfma_f32_16x16x32_bf16(af[ks][i2], bf[ks][j], acc[i2][j], 0, 0, 0);
        asm volatile("s_waitcnt vmcnt(0)\ns_barrier" ::: "memory");
    }

    if (C_MODE == 0) {
        float* C = (float*)Cv;
#pragma unroll
        for (int i2 = 0; i2 < MF; ++i2)
#pragma unroll
            for (int j = 0; j < 4; ++j)
#pragma unroll
                for (int v = 0; v < 4; ++v) {
                    int row = bm + wr * (TM / 2) + i2 * 16 + g * 4 + v;
                    int col = bn + wc * 64 + j * 16 + l15;
                    C[(size_t)row * N + col] = acc[i2][j][v];
                }
    } else {
        unsigned short* C = (unsigned short*)Cv;
        float s = (bn < 1024) ? SC_Q : 1.0f;
#pragma unroll
        for (int i2 = 0; i2 < MF; ++i2)
#pragma unroll
            for (int j = 0; j < 4; ++j)
#pragma unroll
                for (int v = 0; v < 4; ++v) {
                    int row = bm + wr * (TM / 2) + i2 * 16 + g * 4 + v;
                    int col = bn + wc * 64 + j * 16 + l15;
                    C[(size_t)row * N + col] = f2bf(acc[i2][j][v] * s);
                }
    }
}

// ---------------------------------------------------------------------------
// V transpose: qkv V-part [token][d] -> vt[(b*8+h)*128 + d][token]
// ---------------------------------------------------------------------------
__global__ __launch_bounds__(256) void transpose_v(const unsigned short* __restrict__ qkv,
                                                   unsigned short* __restrict__ vt) {
    __shared__ unsigned short T[64][72];
    const int t0 = blockIdx.x * 64, d0 = blockIdx.y * 64, bh = blockIdx.z;
    const int b = bh >> 3, h = bh & 7;
    const int tid = threadIdx.x;
#pragma unroll
    for (int p = 0; p < 2; ++p) {
        int r = p * 32 + (tid >> 3), c = tid & 7;
        *(short8*)&T[r][c * 8] =
            *(const short8*)(qkv + (size_t)(b * SEQ + t0 + r) * FQKV + 2048 + h * 128 + d0 + c * 8);
    }
    __syncthreads();
#pragma unroll
    for (int p = 0; p < 2; ++p) {
        int d = p * 32 + (tid >> 3), c = tid & 7;
        short8 v;
#pragma unroll
        for (int j = 0; j < 8; ++j) v[j] = (short)T[c * 8 + j][d];
        *(short8*)(vt + (size_t)(bh * 128 + d0 + d) * SEQ + t0 + c * 8) = v;
    }
}

// ---------------------------------------------------------------------------
// Flash attention (R15-exact, best measured 48.2us): R9 structure + cvt_pk
// P-packing. R16's manual address hoisting measured null-to-negative
// (compiler already LICM's) and is reverted. This 2-barrier structure's
// floor is ~48us (LDS-port + barrier interleave); next lever = T16 rewrite.
// ---------------------------------------------------------------------------
__global__ __launch_bounds__(256) void attn_mfma(const unsigned short* __restrict__ qkv,
                                                 const unsigned short* __restrict__ vt,
                                                 unsigned short* __restrict__ ao,
                                                 unsigned short* __restrict__ po,
                                                 float* __restrict__ pml) {
    __shared__ unsigned short Ks[64 * 128];
    __shared__ unsigned short Vs[128 * 64];
    __shared__ unsigned short Ps[4][16 * 64];
    const int h = blockIdx.y, b = blockIdx.z;
    const int x = blockIdx.x;
    int qblk, s, nsp;
    if (x < 30)      { qblk = 27 - x / 3;               s = x % 3;  nsp = 3; }
    else if (x < 46) { int i = x - 30; qblk = 31 - (i >> 2); s = i & 3; nsp = 4; }
    else if (x < 64) { int i = x - 46; qblk = 17 - (i >> 1); s = i & 1; nsp = 2; }
    else             { qblk = 72 - x;                   s = 0;      nsp = 1; }
    const int T = qblk + 1;
    const int jb0 = (s * T) / nsp, jb1 = ((s + 1) * T) / nsp;
    const int split = (nsp > 1);
    const int slot = ((b * 8 + h) << 6) + x;          // valid when split (x<64)

    const int tid = threadIdx.x, lane = tid & 63, wv = tid >> 6;
    const int l15 = lane & 15, g = lane >> 4;
    const int q0 = qblk * 64;
    const int qrow = q0 + wv * 16 + l15;

    auto stageK = [&](int jb) {
#pragma unroll
        for (int inst = 0; inst < 4; ++inst) {
            int ci = inst * 256 + wv * 64 + lane;
            int rowk = ci >> 4, ck = ci & 15;
            gl_lds16(qkv + (size_t)(b * SEQ + jb * 64 + rowk) * FQKV + 1024 + h * 128
                         + ((ck ^ (rowk & 7)) << 3),
                     &Ks[(inst * 256 + wv * 64) * 8]);
        }
    };
    auto stageV = [&](int jb) {
#pragma unroll
        for (int inst = 0; inst < 4; ++inst) {
            int ci = inst * 256 + wv * 64 + lane;
            int rowv = ci >> 3, cv = ci & 7;
            gl_lds16(vt + (size_t)((b * 8 + h) * 128 + rowv) * SEQ + jb * 64
                        + ((cv ^ (rowv & 7)) << 3),
                     &Vs[(inst * 256 + wv * 64) * 8]);
        }
    };

    short8 qf[4];
    {
        const unsigned short* qb = qkv + (size_t)(b * SEQ + qrow) * FQKV + h * 128;
#pragma unroll
        for (int ks = 0; ks < 4; ++ks) qf[ks] = *(const short8*)(qb + ks * 32 + g * 8);
    }

    float m_r = -1e30f, l_r = 0.f;
    f32x4 o[8] = {};

    stageK(jb0);
    __syncthreads();

    for (int jb = jb0; jb < jb1; ++jb) {
        stageV(jb);

        f32x4 sv[4] = {};
        __builtin_amdgcn_s_setprio(1);
#pragma unroll
        for (int ks = 0; ks < 4; ++ks) {
#pragma unroll
            for (int fi = 0; fi < 4; ++fi) {
                int rk = fi * 16 + l15;
                short8 kf = *(const short8*)&Ks[rk * 128 + (((ks * 4 + g) ^ (rk & 7)) << 3)];
                sv[fi] = __builtin_amdgcn_mfma_f32_16x16x32_bf16(kf, qf[ks], sv[fi], 0, 0, 0);
            }
        }
        __builtin_amdgcn_s_setprio(0);

        if (jb == qblk) {
#pragma unroll
            for (int fi = 0; fi < 4; ++fi)
#pragma unroll
                for (int v = 0; v < 4; ++v) {
                    int kv = q0 + fi * 16 + g * 4 + v;
                    if (kv > qrow) sv[fi][v] = -1e30f;
                }
        }

        float mx = -1e30f;
#pragma unroll
        for (int fi = 0; fi < 4; ++fi)
            mx = fmaxf(mx, fmaxf(fmaxf(sv[fi][0], sv[fi][1]), fmaxf(sv[fi][2], sv[fi][3])));
        mx = fmaxf(mx, __shfl_xor(mx, 16));
        mx = fmaxf(mx, __shfl_xor(mx, 32));
        if (__any(mx - m_r > 16.0f)) {
            float Mn = fmaxf(m_r, mx);
            float alpha = exp2f(m_r - Mn);
            l_r *= alpha;
            float av[4];
#pragma unroll
            for (int v = 0; v < 4; ++v) av[v] = __shfl(alpha, g * 4 + v);
#pragma unroll
            for (int fn = 0; fn < 8; ++fn) {
                o[fn][0] *= av[0]; o[fn][1] *= av[1]; o[fn][2] *= av[2]; o[fn][3] *= av[3];
            }
            m_r = Mn;
        }

        float ps = 0.f;
#pragma unroll
        for (int fi = 0; fi < 4; ++fi) {
#pragma unroll
            for (int p2 = 0; p2 < 2; ++p2) {
                float e0 = exp2f(sv[fi][2 * p2] - m_r);
                float e1 = exp2f(sv[fi][2 * p2 + 1] - m_r);
                ps += e0 + e1;
                unsigned int pk;
                asm("v_cvt_pk_bf16_f32 %0, %1, %2" : "=v"(pk) : "v"(e0), "v"(e1));
                int kv = fi * 16 + g * 4 + 2 * p2;
                int addr = l15 * 64 + (((kv >> 3) ^ (l15 & 7)) << 3) + (kv & 7);
                *(unsigned int*)&Ps[wv][addr] = pk;
            }
        }
        ps += __shfl_xor(ps, 16);
        ps += __shfl_xor(ps, 32);
        l_r += ps;

        __syncthreads();
        if (jb + 1 < jb1) stageK(jb + 1);

        __builtin_amdgcn_s_setprio(1);
#pragma unroll
        for (int ks = 0; ks < 2; ++ks) {
            short8 pa = *(const short8*)&Ps[wv][l15 * 64 + (((ks * 4 + g) ^ (l15 & 7)) << 3)];
#pragma unroll
            for (int fn = 0; fn < 8; ++fn) {
                int rv = fn * 16 + l15;
                short8 vf = *(const short8*)&Vs[rv * 64 + (((ks * 4 + g) ^ (rv & 7)) << 3)];
                o[fn] = __builtin_amdgcn_mfma_f32_16x16x32_bf16(pa, vf, o[fn], 0, 0, 0);
            }
        }
        __builtin_amdgcn_s_setprio(0);

        __syncthreads();
    }

    if (split) {
        unsigned short* od = po + (size_t)slot * 8192;   // bf16 partial O
#pragma unroll
        for (int fn = 0; fn < 8; ++fn)
#pragma unroll
            for (int v = 0; v < 4; ++v)
                od[(wv * 16 + g * 4 + v) * 128 + fn * 16 + l15] = f2bf(o[fn][v]);
        if (g == 0) {
            pml[(size_t)slot * 128 + wv * 16 + l15] = m_r;
            pml[(size_t)slot * 128 + 64 + wv * 16 + l15] = l_r;
        }
    } else {
        float lv[4];
#pragma unroll
        for (int v = 0; v < 4; ++v) lv[v] = 1.0f / __shfl(l_r, g * 4 + v);
#pragma unroll
        for (int fn = 0; fn < 8; ++fn)
#pragma unroll
            for (int v = 0; v < 4; ++v) {
                int row = b * SEQ + q0 + wv * 16 + g * 4 + v;
                ao[(size_t)row * DIM + h * 128 + fn * 16 + l15] = f2bf(o[fn][v] * lv[v]);
            }
    }
}

// ---------------------------------------------------------------------------
// Combine n in {2,3,4} KV-split partials -> normalized bf16 output (R9).
// ---------------------------------------------------------------------------
__global__ __launch_bounds__(256) void attn_combine(const unsigned short* __restrict__ po,
                                                    const float* __restrict__ pml,
                                                    unsigned short* __restrict__ ao) {
    const int qblk = 9 + blockIdx.x, h = blockIdx.y, b = blockIdx.z;
    int base, n;
    if (qblk >= 28)      { base = 30 + (31 - qblk) * 4; n = 4; }
    else if (qblk >= 18) { base = (27 - qblk) * 3;      n = 3; }
    else                 { base = 46 + (17 - qblk) * 2; n = 2; }
    const int slot0 = ((b * 8 + h) << 6) + base;
    const int row = threadIdx.x >> 2, dp = threadIdx.x & 3;

    float M = -1e30f;
#pragma unroll
    for (int s2 = 0; s2 < 4; ++s2)
        if (s2 < n) M = fmaxf(M, pml[(size_t)(slot0 + s2) * 128 + row]);
    float denom = 0.f;
#pragma unroll
    for (int s2 = 0; s2 < 4; ++s2)
        if (s2 < n) denom += exp2f(pml[(size_t)(slot0 + s2) * 128 + row] - M)
                             * pml[(size_t)(slot0 + s2) * 128 + 64 + row];
    float inv = 1.0f / denom;

    float acc[32] = {};
#pragma unroll
    for (int s2 = 0; s2 < 4; ++s2)
        if (s2 < n) {
            float wgt = exp2f(pml[(size_t)(slot0 + s2) * 128 + row] - M) * inv;
            const unsigned short* ob = po + (size_t)(slot0 + s2) * 8192 + row * 128 + dp * 32;
#pragma unroll
            for (int j = 0; j < 4; ++j) {
                short8 pv = *(const short8*)(ob + j * 8);
#pragma unroll
                for (int e = 0; e < 8; ++e)
                    acc[j * 8 + e] += wgt * bf2f((unsigned short)pv[e]);
            }
        }

    unsigned short* dst = ao + ((size_t)(b * SEQ + qblk * 64 + row)) * DIM + h * 128 + dp * 32;
#pragma unroll
    for (int j = 0; j < 4; ++j) {
        short8 r;
#pragma unroll
        for (int e = 0; e < 8; ++e) r[e] = (short)f2bf(acc[j * 8 + e]);
        *(short8*)(dst + j * 8) = r;
    }
}

// ---------------------------------------------------------------------------
extern "C" void kernel_launch(void* const* d_in, const int* in_sizes, int n_in,
                              void* d_out, int out_size, void* d_ws, size_t ws_size,
                              hipStream_t stream) {
    const float* x     = (const float*)d_in[0];
    const float* gamma = (const float*)d_in[1];
    const float* w_qkv = (const float*)d_in[2];
    const float* w_out = (const float*)d_in[3];

    char* ws = (char*)d_ws;
    unsigned short* qkvb = (unsigned short*)ws;                   // 25165824 B  [4096][3072]
    unsigned short* vtb  = (unsigned short*)(ws + 25165824);      //  8388608 B  [16][128][2048]
    unsigned short* xnb  = (unsigned short*)(ws + 33554432);      //  8388608 B  [4096][1024]
    unsigned short* wqb  = (unsigned short*)(ws + 41943040);      //  6291456 B  [3072][1024]
    unsigned short* wob  = (unsigned short*)(ws + 48234496);      //  2097152 B  [1024][1024]
    unsigned short* aob  = (unsigned short*)(ws + 50331648);      //  8388608 B  [4096][1024]
    // pml overlaps wqb (dead after gemm1): 1024 slots x 128 f32 = 512 KB
    float*          pml  = (float*)(ws + 41943040);
    unsigned short* po   = (unsigned short*)d_out;  // 1024 slots x 64x128 bf16 = 16.78 MB

    prep<<<8192, 256, 0, stream>>>(x, gamma, xnb, w_qkv, wqb, w_out, wob);
    gemm_bf16<1, 128, 2><<<dim3(24, 32), 256, 0, stream>>>(xnb, wqb, qkvb, NTOK, FQKV, DIM);
    transpose_v<<<dim3(32, 2, 16), 256, 0, stream>>>(qkvb, vtb);
    attn_mfma<<<dim3(73, 8, 2), 256, 0, stream>>>(qkvb, vtb, aob, po, pml);
    attn_combine<<<dim3(23, 8, 2), 256, 0, stream>>>(po, pml, aob);
    gemm_bf16<0, 64, 1><<<dim3(8, 64), 256, 0, stream>>>(aob, wob, (float*)d_out, NTOK, DIM, DIM);
}

// Round 18
// 111.552 us; speedup vs baseline: 1.0655x; 1.0389x over previous
//
#include <hip/hip_runtime.h>

#define SEQ 2048
#define NTOK 4096
#define DIM 1024
#define FQKV 3072
#define SC_Q (0.08838834764831843f * 1.4426950408889634f)  // 128^-.5 * log2e
#define SC_NORM 32.0f                  // sqrt(1024)

typedef short short8 __attribute__((ext_vector_type(8)));
typedef float f32x4 __attribute__((ext_vector_type(4)));
typedef unsigned short u16x4 __attribute__((ext_vector_type(4)));

__device__ __forceinline__ unsigned short f2bf(float f) {
    unsigned int u = __float_as_uint(f);
    u += 0x7fffu + ((u >> 16) & 1u);   // RNE
    return (unsigned short)(u >> 16);
}
__device__ __forceinline__ float bf2f(unsigned short b) {
    return __uint_as_float(((unsigned int)b) << 16);
}
__device__ __forceinline__ void gl_lds16(const void* g, void* l) {
    __builtin_amdgcn_global_load_lds((const __attribute__((address_space(1))) void*)g,
                                     (__attribute__((address_space(3))) void*)l, 16, 0, 0);
}

// ---------------------------------------------------------------------------
// prep: blocks [0,4096) = L2-norm per token; blocks [4096,8192) = weight conv
// ---------------------------------------------------------------------------
__global__ __launch_bounds__(256) void prep(const float* __restrict__ x,
                                            const float* __restrict__ gamma,
                                            unsigned short* __restrict__ xn,
                                            const float* __restrict__ wq,
                                            unsigned short* __restrict__ wqb,
                                            const float* __restrict__ wo,
                                            unsigned short* __restrict__ wob) {
    if (blockIdx.x < 4096) {
        int token = blockIdx.x;
        float4 v = ((const float4*)(x + (size_t)token * DIM))[threadIdx.x];
        float ss = v.x * v.x + v.y * v.y + v.z * v.z + v.w * v.w;
#pragma unroll
        for (int off = 32; off > 0; off >>= 1) ss += __shfl_down(ss, off);
        __shared__ float wsum[4];
        if ((threadIdx.x & 63) == 0) wsum[threadIdx.x >> 6] = ss;
        __syncthreads();
        float tot = wsum[0] + wsum[1] + wsum[2] + wsum[3];
        float sc = SC_NORM / fmaxf(sqrtf(tot), 1e-12f);
        float4 g = ((const float4*)gamma)[threadIdx.x];
        u16x4 o;
        o.x = f2bf(v.x * sc * g.x);
        o.y = f2bf(v.y * sc * g.y);
        o.z = f2bf(v.z * sc * g.z);
        o.w = f2bf(v.w * sc * g.w);
        ((u16x4*)(xn + (size_t)token * DIM))[threadIdx.x] = o;
    } else {
        int i = (blockIdx.x - 4096) * 256 + threadIdx.x;   // f4 index, 1048576 total
        const float* w; unsigned short* o; int idx;
        if (i < 786432) { w = wq; o = wqb; idx = i; }
        else            { w = wo; o = wob; idx = i - 786432; }
        float4 v = ((const float4*)w)[idx];
        u16x4 r;
        r.x = f2bf(v.x); r.y = f2bf(v.y); r.z = f2bf(v.z); r.w = f2bf(v.w);
        ((u16x4*)o)[idx] = r;
    }
}

// ---------------------------------------------------------------------------
// bf16 GEMM NT (R8 inner loop): TM x 128 tile, BK=64, single-buffer split-
// phase raw barriers, 2D XCD chunking. NEW: for C_MODE==1 V-blocks
// (bn >= 2048) the epilogue transposes the tile through LDS (Smem reuse,
// stride 136) and writes vt[(b*8+h)*128+d][tok] directly — eliminates the
// separate transpose_v kernel and qkvb's V-third round-trip (~25 MB).
// ---------------------------------------------------------------------------
template<int C_MODE, int TM, int XC>
__global__ __launch_bounds__(256) void gemm_bf16(const unsigned short* __restrict__ A,
                                                 const unsigned short* __restrict__ B,
                                                 void* __restrict__ Cv,
                                                 unsigned short* __restrict__ vtout,
                                                 int M, int N, int K) {
    constexpr int MF = TM / 32;
    __shared__ unsigned short Smem[TM * 64 + 128 * 64];
    unsigned short* As = Smem;
    unsigned short* Bs = Smem + TM * 64;

    // 2D-chunked XCD swizzle (bijective; assumes block n -> XCD n%8)
    int lin = blockIdx.y * gridDim.x + blockIdx.x;
    int xcd = lin & 7, i = lin >> 3;
    int CW = gridDim.x / XC;               // chunk width (tiles)
    int CH = gridDim.y / (8 / XC);         // chunk height (tiles)
    int bx = (xcd % XC) * CW + (i % CW);
    int by = (xcd / XC) * CH + (i / CW);

    const int bn = bx * 128, bm = by * TM;
    const int tid = threadIdx.x, lane = tid & 63, wv = tid >> 6;
    const int wr = wv >> 1, wc = wv & 1;
    const int l15 = lane & 15, g = lane >> 4;

    f32x4 acc[MF][4] = {};

    auto stage = [&](int k0) {
#pragma unroll
        for (int ia = 0; ia < TM / 32; ++ia) {
            int ci = ia * 256 + wv * 64 + lane;
            int row = ci >> 3, cc = ci & 7;
            int co = (cc ^ (row & 7)) << 3;
            gl_lds16(A + (size_t)(bm + row) * K + k0 + co, &As[(ia * 256 + wv * 64) * 8]);
        }
#pragma unroll
        for (int ib = 0; ib < 4; ++ib) {
            int ci = ib * 256 + wv * 64 + lane;
            int row = ci >> 3, cc = ci & 7;
            int co = (cc ^ (row & 7)) << 3;
            gl_lds16(B + (size_t)(bn + row) * K + k0 + co, &Bs[(ib * 256 + wv * 64) * 8]);
        }
    };

    stage(0);
    asm volatile("s_waitcnt vmcnt(0)\ns_barrier" ::: "memory");

    for (int k0 = 0; k0 < K; k0 += 64) {
        short8 af[2][MF], bf[2][4];
#pragma unroll
        for (int ks = 0; ks < 2; ++ks) {
#pragma unroll
            for (int f = 0; f < MF; ++f) {
                int ra = wr * (TM / 2) + f * 16 + l15;
                af[ks][f] = *(const short8*)&As[ra * 64 + (((ks * 4 + g) ^ (ra & 7)) << 3)];
            }
#pragma unroll
            for (int f = 0; f < 4; ++f) {
                int rb = wc * 64 + f * 16 + l15;
                bf[ks][f] = *(const short8*)&Bs[rb * 64 + (((ks * 4 + g) ^ (rb & 7)) << 3)];
            }
        }
        asm volatile("s_waitcnt lgkmcnt(0)\ns_barrier" ::: "memory");
        if (k0 + 64 < K) stage(k0 + 64);
#pragma unroll
        for (int ks = 0; ks < 2; ++ks)
#pragma unroll
            for (int i2 = 0; i2 < MF; ++i2)
#pragma unroll
                for (int j = 0; j < 4; ++j)
                    acc[i2][j] = __builtin_amdgcn_mfma_f32_16x16x32_bf16(af[ks][i2], bf[ks][j], acc[i2][j], 0, 0, 0);
        asm volatile("s_waitcnt vmcnt(0)\ns_barrier" ::: "memory");
    }

    if (C_MODE == 1 && bn >= 2048) {
        // ---- fused V transpose: tile rows = tokens, cols = v-dims ----
        const int b_ = bm >> 11;                 // tile fully inside one batch
        const int tokbase = bm & 2047;
        const int h_ = (bn - 2048) >> 7;         // tile fully inside one head
        unsigned short* vbase = vtout + ((size_t)(b_ * 8 + h_) * 128) * SEQ;
#pragma unroll
        for (int p = 0; p < 2; ++p) {            // column halves (wc == p owns)
            if (p) __syncthreads();              // Tb reuse between passes
            if (wc == p) {
#pragma unroll
                for (int i2 = 0; i2 < MF; ++i2)
#pragma unroll
                    for (int j = 0; j < 4; ++j)
#pragma unroll
                        for (int v = 0; v < 4; ++v) {
                            int tok_l = wr * 64 + i2 * 16 + g * 4 + v;
                            int col_l = j * 16 + l15;            // 0..63
                            Smem[col_l * 136 + tok_l] = f2bf(acc[i2][j][v]);
                        }
            }
            __syncthreads();
#pragma unroll
            for (int dd = 0; dd < 4; ++dd) {
                int d_loc = (tid >> 4) + dd * 16;                // 0..63
                int toff = (tid & 15) * 8;                       // 0..120
                short8 vvv = *(const short8*)&Smem[d_loc * 136 + toff];
                *(short8*)(vbase + (size_t)(p * 64 + d_loc) * SEQ + tokbase + toff) = vvv;
            }
        }
    } else if (C_MODE == 0) {
        float* C = (float*)Cv;
#pragma unroll
        for (int i2 = 0; i2 < MF; ++i2)
#pragma unroll
            for (int j = 0; j < 4; ++j)
#pragma unroll
                for (int v = 0; v < 4; ++v) {
                    int row = bm + wr * (TM / 2) + i2 * 16 + g * 4 + v;
                    int col = bn + wc * 64 + j * 16 + l15;
                    C[(size_t)row * N + col] = acc[i2][j][v];
                }
    } else {
        unsigned short* C = (unsigned short*)Cv;
        float s = (bn < 1024) ? SC_Q : 1.0f;
#pragma unroll
        for (int i2 = 0; i2 < MF; ++i2)
#pragma unroll
            for (int j = 0; j < 4; ++j)
#pragma unroll
                for (int v = 0; v < 4; ++v) {
                    int row = bm + wr * (TM / 2) + i2 * 16 + g * 4 + v;
                    int col = bn + wc * 64 + j * 16 + l15;
                    C[(size_t)row * N + col] = f2bf(acc[i2][j][v] * s);
                }
    }
}

// ---------------------------------------------------------------------------
// Flash attention (R15-exact, best measured ~48us): R9 structure + cvt_pk
// P-packing. 2-barrier structural floor; T16 rewrite is the only deeper lever.
// ---------------------------------------------------------------------------
__global__ __launch_bounds__(256) void attn_mfma(const unsigned short* __restrict__ qkv,
                                                 const unsigned short* __restrict__ vt,
                                                 unsigned short* __restrict__ ao,
                                                 unsigned short* __restrict__ po,
                                                 float* __restrict__ pml) {
    __shared__ unsigned short Ks[64 * 128];
    __shared__ unsigned short Vs[128 * 64];
    __shared__ unsigned short Ps[4][16 * 64];
    const int h = blockIdx.y, b = blockIdx.z;
    const int x = blockIdx.x;
    int qblk, s, nsp;
    if (x < 30)      { qblk = 27 - x / 3;               s = x % 3;  nsp = 3; }
    else if (x < 46) { int i = x - 30; qblk = 31 - (i >> 2); s = i & 3; nsp = 4; }
    else if (x < 64) { int i = x - 46; qblk = 17 - (i >> 1); s = i & 1; nsp = 2; }
    else             { qblk = 72 - x;                   s = 0;      nsp = 1; }
    const int T = qblk + 1;
    const int jb0 = (s * T) / nsp, jb1 = ((s + 1) * T) / nsp;
    const int split = (nsp > 1);
    const int slot = ((b * 8 + h) << 6) + x;          // valid when split (x<64)

    const int tid = threadIdx.x, lane = tid & 63, wv = tid >> 6;
    const int l15 = lane & 15, g = lane >> 4;
    const int q0 = qblk * 64;
    const int qrow = q0 + wv * 16 + l15;

    auto stageK = [&](int jb) {
#pragma unroll
        for (int inst = 0; inst < 4; ++inst) {
            int ci = inst * 256 + wv * 64 + lane;
            int rowk = ci >> 4, ck = ci & 15;
            gl_lds16(qkv + (size_t)(b * SEQ + jb * 64 + rowk) * FQKV + 1024 + h * 128
                         + ((ck ^ (rowk & 7)) << 3),
                     &Ks[(inst * 256 + wv * 64) * 8]);
        }
    };
    auto stageV = [&](int jb) {
#pragma unroll
        for (int inst = 0; inst < 4; ++inst) {
            int ci = inst * 256 + wv * 64 + lane;
            int rowv = ci >> 3, cv = ci & 7;
            gl_lds16(vt + (size_t)((b * 8 + h) * 128 + rowv) * SEQ + jb * 64
                        + ((cv ^ (rowv & 7)) << 3),
                     &Vs[(inst * 256 + wv * 64) * 8]);
        }
    };

    short8 qf[4];
    {
        const unsigned short* qb = qkv + (size_t)(b * SEQ + qrow) * FQKV + h * 128;
#pragma unroll
        for (int ks = 0; ks < 4; ++ks) qf[ks] = *(const short8*)(qb + ks * 32 + g * 8);
    }

    float m_r = -1e30f, l_r = 0.f;
    f32x4 o[8] = {};

    stageK(jb0);
    __syncthreads();

    for (int jb = jb0; jb < jb1; ++jb) {
        stageV(jb);

        f32x4 sv[4] = {};
        __builtin_amdgcn_s_setprio(1);
#pragma unroll
        for (int ks = 0; ks < 4; ++ks) {
#pragma unroll
            for (int fi = 0; fi < 4; ++fi) {
                int rk = fi * 16 + l15;
                short8 kf = *(const short8*)&Ks[rk * 128 + (((ks * 4 + g) ^ (rk & 7)) << 3)];
                sv[fi] = __builtin_amdgcn_mfma_f32_16x16x32_bf16(kf, qf[ks], sv[fi], 0, 0, 0);
            }
        }
        __builtin_amdgcn_s_setprio(0);

        if (jb == qblk) {
#pragma unroll
            for (int fi = 0; fi < 4; ++fi)
#pragma unroll
                for (int v = 0; v < 4; ++v) {
                    int kv = q0 + fi * 16 + g * 4 + v;
                    if (kv > qrow) sv[fi][v] = -1e30f;
                }
        }

        float mx = -1e30f;
#pragma unroll
        for (int fi = 0; fi < 4; ++fi)
            mx = fmaxf(mx, fmaxf(fmaxf(sv[fi][0], sv[fi][1]), fmaxf(sv[fi][2], sv[fi][3])));
        mx = fmaxf(mx, __shfl_xor(mx, 16));
        mx = fmaxf(mx, __shfl_xor(mx, 32));
        if (__any(mx - m_r > 16.0f)) {
            float Mn = fmaxf(m_r, mx);
            float alpha = exp2f(m_r - Mn);
            l_r *= alpha;
            float av[4];
#pragma unroll
            for (int v = 0; v < 4; ++v) av[v] = __shfl(alpha, g * 4 + v);
#pragma unroll
            for (int fn = 0; fn < 8; ++fn) {
                o[fn][0] *= av[0]; o[fn][1] *= av[1]; o[fn][2] *= av[2]; o[fn][3] *= av[3];
            }
            m_r = Mn;
        }

        float ps = 0.f;
#pragma unroll
        for (int fi = 0; fi < 4; ++fi) {
#pragma unroll
            for (int p2 = 0; p2 < 2; ++p2) {
                float e0 = exp2f(sv[fi][2 * p2] - m_r);
                float e1 = exp2f(sv[fi][2 * p2 + 1] - m_r);
                ps += e0 + e1;
                unsigned int pk;
                asm("v_cvt_pk_bf16_f32 %0, %1, %2" : "=v"(pk) : "v"(e0), "v"(e1));
                int kv = fi * 16 + g * 4 + 2 * p2;
                int addr = l15 * 64 + (((kv >> 3) ^ (l15 & 7)) << 3) + (kv & 7);
                *(unsigned int*)&Ps[wv][addr] = pk;
            }
        }
        ps += __shfl_xor(ps, 16);
        ps += __shfl_xor(ps, 32);
        l_r += ps;

        __syncthreads();
        if (jb + 1 < jb1) stageK(jb + 1);

        __builtin_amdgcn_s_setprio(1);
#pragma unroll
        for (int ks = 0; ks < 2; ++ks) {
            short8 pa = *(const short8*)&Ps[wv][l15 * 64 + (((ks * 4 + g) ^ (l15 & 7)) << 3)];
#pragma unroll
            for (int fn = 0; fn < 8; ++fn) {
                int rv = fn * 16 + l15;
                short8 vf = *(const short8*)&Vs[rv * 64 + (((ks * 4 + g) ^ (rv & 7)) << 3)];
                o[fn] = __builtin_amdgcn_mfma_f32_16x16x32_bf16(pa, vf, o[fn], 0, 0, 0);
            }
        }
        __builtin_amdgcn_s_setprio(0);

        __syncthreads();
    }

    if (split) {
        unsigned short* od = po + (size_t)slot * 8192;   // bf16 partial O
#pragma unroll
        for (int fn = 0; fn < 8; ++fn)
#pragma unroll
            for (int v = 0; v < 4; ++v)
                od[(wv * 16 + g * 4 + v) * 128 + fn * 16 + l15] = f2bf(o[fn][v]);
        if (g == 0) {
            pml[(size_t)slot * 128 + wv * 16 + l15] = m_r;
            pml[(size_t)slot * 128 + 64 + wv * 16 + l15] = l_r;
        }
    } else {
        float lv[4];
#pragma unroll
        for (int v = 0; v < 4; ++v) lv[v] = 1.0f / __shfl(l_r, g * 4 + v);
#pragma unroll
        for (int fn = 0; fn < 8; ++fn)
#pragma unroll
            for (int v = 0; v < 4; ++v) {
                int row = b * SEQ + q0 + wv * 16 + g * 4 + v;
                ao[(size_t)row * DIM + h * 128 + fn * 16 + l15] = f2bf(o[fn][v] * lv[v]);
            }
    }
}

// ---------------------------------------------------------------------------
// Combine n in {2,3,4} KV-split partials -> normalized bf16 output (R9).
// ---------------------------------------------------------------------------
__global__ __launch_bounds__(256) void attn_combine(const unsigned short* __restrict__ po,
                                                    const float* __restrict__ pml,
                                                    unsigned short* __restrict__ ao) {
    const int qblk = 9 + blockIdx.x, h = blockIdx.y, b = blockIdx.z;
    int base, n;
    if (qblk >= 28)      { base = 30 + (31 - qblk) * 4; n = 4; }
    else if (qblk >= 18) { base = (27 - qblk) * 3;      n = 3; }
    else                 { base = 46 + (17 - qblk) * 2; n = 2; }
    const int slot0 = ((b * 8 + h) << 6) + base;
    const int row = threadIdx.x >> 2, dp = threadIdx.x & 3;

    float M = -1e30f;
#pragma unroll
    for (int s2 = 0; s2 < 4; ++s2)
        if (s2 < n) M = fmaxf(M, pml[(size_t)(slot0 + s2) * 128 + row]);
    float denom = 0.f;
#pragma unroll
    for (int s2 = 0; s2 < 4; ++s2)
        if (s2 < n) denom += exp2f(pml[(size_t)(slot0 + s2) * 128 + row] - M)
                             * pml[(size_t)(slot0 + s2) * 128 + 64 + row];
    float inv = 1.0f / denom;

    float acc[32] = {};
#pragma unroll
    for (int s2 = 0; s2 < 4; ++s2)
        if (s2 < n) {
            float wgt = exp2f(pml[(size_t)(slot0 + s2) * 128 + row] - M) * inv;
            const unsigned short* ob = po + (size_t)(slot0 + s2) * 8192 + row * 128 + dp * 32;
#pragma unroll
            for (int j = 0; j < 4; ++j) {
                short8 pv = *(const short8*)(ob + j * 8);
#pragma unroll
                for (int e = 0; e < 8; ++e)
                    acc[j * 8 + e] += wgt * bf2f((unsigned short)pv[e]);
            }
        }

    unsigned short* dst = ao + ((size_t)(b * SEQ + qblk * 64 + row)) * DIM + h * 128 + dp * 32;
#pragma unroll
    for (int j = 0; j < 4; ++j) {
        short8 r;
#pragma unroll
        for (int e = 0; e < 8; ++e) r[e] = (short)f2bf(acc[j * 8 + e]);
        *(short8*)(dst + j * 8) = r;
    }
}

// ---------------------------------------------------------------------------
extern "C" void kernel_launch(void* const* d_in, const int* in_sizes, int n_in,
                              void* d_out, int out_size, void* d_ws, size_t ws_size,
                              hipStream_t stream) {
    const float* x     = (const float*)d_in[0];
    const float* gamma = (const float*)d_in[1];
    const float* w_qkv = (const float*)d_in[2];
    const float* w_out = (const float*)d_in[3];

    char* ws = (char*)d_ws;
    unsigned short* qkvb = (unsigned short*)ws;                   // 25165824 B  [4096][3072] (V third unused)
    unsigned short* vtb  = (unsigned short*)(ws + 25165824);      //  8388608 B  [16][128][2048]
    unsigned short* xnb  = (unsigned short*)(ws + 33554432);      //  8388608 B  [4096][1024]
    unsigned short* wqb  = (unsigned short*)(ws + 41943040);      //  6291456 B  [3072][1024]
    unsigned short* wob  = (unsigned short*)(ws + 48234496);      //  2097152 B  [1024][1024]
    unsigned short* aob  = (unsigned short*)(ws + 50331648);      //  8388608 B  [4096][1024]
    // pml overlaps wqb (dead after gemm1): 1024 slots x 128 f32 = 512 KB
    float*          pml  = (float*)(ws + 41943040);
    unsigned short* po   = (unsigned short*)d_out;  // 1024 slots x 64x128 bf16 = 16.78 MB

    prep<<<8192, 256, 0, stream>>>(x, gamma, xnb, w_qkv, wqb, w_out, wob);
    gemm_bf16<1, 128, 2><<<dim3(24, 32), 256, 0, stream>>>(xnb, wqb, qkvb, vtb, NTOK, FQKV, DIM);
    attn_mfma<<<dim3(73, 8, 2), 256, 0, stream>>>(qkvb, vtb, aob, po, pml);
    attn_combine<<<dim3(23, 8, 2), 256, 0, stream>>>(po, pml, aob);
    gemm_bf16<0, 64, 1><<<dim3(8, 64), 256, 0, stream>>>(aob, wob, (float*)d_out, nullptr, NTOK, DIM, DIM);
}